// Round 6
// baseline (137.876 us; speedup 1.0000x reference)
//
#include <hip/hip_runtime.h>
#include <stdint.h>

// Sparse top-k attention, B=1 S=2048 H=16 D=128 N_KV=8192 K=512.
// R6: ZERO LDS in the key loop. The P (C->A layout) and V (row->B-frag)
// conversions are both 16x16 transposes, done with identity-MFMAs:
//   D = A_nat * I  lands in C-layout (lane=col) = exactly the PV operand
// layout. V path is bit-exact (bf16->f32->truncate). Gather is 8x dwordx2
// per 16-key tile so lanes' chunks are directly K=16 MFMA fragments; QK is
// 8x mfma_f32_16x16x16bf16_1k. R5's DS-pipe tax (256 scalar ds_read_u16 per
// wave, ~28 us/CU of serialized LDS) disappears. Double-buffered gather.

typedef float  f32x4 __attribute__((ext_vector_type(4)));
typedef short  s16x4 __attribute__((ext_vector_type(4)));

#define S_LEN   2048
#define N_HEADS 16
#define D_HEAD  128
#define TOPK    512

// LDS (epilogue only): OA [16][132] f32 at 0, OB at 8448, lsum[64] at 16896
#define SMEM_BYTES 17152

// fp32 -> bf16 round-nearest-even
__device__ __forceinline__ unsigned short f2bf(float f) {
  union { float f; unsigned u; } v; v.f = f;
  return (unsigned short)((v.u + 0x7fffu + ((v.u >> 16) & 1u)) >> 16);
}

// pack high16(lo_elem), high16(hi_elem) -> [hi16(hi)|hi16(lo)] (RTZ bf16 pair)
__device__ __forceinline__ unsigned pk_hi16(float lo, float hi) {
  union { float f; unsigned u; } a, b;
  a.f = lo; b.f = hi;
  return __builtin_amdgcn_perm(b.u, a.u, 0x07060302u);
}

__device__ __forceinline__ s16x4 mk_s16x4(unsigned u0, unsigned u1) {
  union { unsigned u[2]; s16x4 v; } x;
  x.u[0] = u0; x.u[1] = u1;
  return x.v;
}

__global__ void __launch_bounds__(256) kv_cvt_bf16(
    const float* __restrict__ kv, unsigned short* __restrict__ o) {
  int i = (blockIdx.x * 256 + threadIdx.x) * 8;   // 8192*128 = 1M elems, grid 512
  float4 a = *(const float4*)(kv + i);
  float4 b = *(const float4*)(kv + i + 4);
  uint4 p;
  p.x = (unsigned)f2bf(a.x) | ((unsigned)f2bf(a.y) << 16);
  p.y = (unsigned)f2bf(a.z) | ((unsigned)f2bf(a.w) << 16);
  p.z = (unsigned)f2bf(b.x) | ((unsigned)f2bf(b.y) << 16);
  p.w = (unsigned)f2bf(b.z) | ((unsigned)f2bf(b.w) << 16);
  *(uint4*)(o + i) = p;
}

__global__ void __launch_bounds__(256, 4) g2core_sparse_attn(
    const float* __restrict__ qg, const unsigned short* __restrict__ kvb,
    const int* __restrict__ tkg, float* __restrict__ outg) {
  __shared__ __align__(16) char smem[SMEM_BYTES];
  float* OA   = (float*)smem;               // [16][132]
  float* OB   = (float*)(smem + 8448);      // [16][132]
  float* lsum = (float*)(smem + 16896);     // [4][16]

  const int s    = blockIdx.x;
  const int tid  = threadIdx.x;
  const int wave = __builtin_amdgcn_readfirstlane(tid >> 6);
  const int lane = tid & 63;
  const int quad = lane >> 4;   // 0..3
  const int n16  = lane & 15;   // 0..15

  // fold 1/sqrt(128) * log2(e) into Q; softmax runs unnormalized in exp2 domain
  const float QSCALE = 0.08838834764831845f * 1.4426950408889634f;

  // ---- Q A-frags (K=16 slices): qf[t2] = A[m=head=n16][k=16*t2+quad*4+j] ----
  s16x4 qf[8];
  {
    const float* qrow = qg + ((size_t)s * N_HEADS + n16) * D_HEAD;
#pragma unroll
    for (int t2 = 0; t2 < 8; ++t2) {
      float4 a = *(const float4*)(qrow + t2 * 16 + quad * 4);
      unsigned u0 = (unsigned)f2bf(a.x * QSCALE) | ((unsigned)f2bf(a.y * QSCALE) << 16);
      unsigned u1 = (unsigned)f2bf(a.z * QSCALE) | ((unsigned)f2bf(a.w * QSCALE) << 16);
      qf[t2] = mk_s16x4(u0, u1);
    }
  }

  // identity B-frag: B[k][n] = (k==n): lane n16 holds j=(quad*4+j==n16)
  s16x4 id_f;
  {
    unsigned u0 = (n16 == quad * 4 + 0 ? 0x3F80u : 0u) | (n16 == quad * 4 + 1 ? 0x3F800000u : 0u);
    unsigned u1 = (n16 == quad * 4 + 2 ? 0x3F80u : 0u) | (n16 == quad * 4 + 3 ? 0x3F800000u : 0u);
    id_f = mk_s16x4(u0, u1);
  }
  // ones-column B-frag: B[k][0]=1 else 0
  s16x4 ones_f;
  {
    unsigned o01 = (n16 == 0) ? 0x3F803F80u : 0u;
    ones_f = mk_s16x4(o01, o01);
  }

  f32x4 o_acc[8];
  f32x4 o_l = (f32x4){0.f, 0.f, 0.f, 0.f};
#pragma unroll
  for (int t = 0; t < 8; ++t) o_acc[t] = (f32x4){0.f, 0.f, 0.f, 0.f};

  const int* tk = tkg + (size_t)s * TOPK + wave * 128;

  // double-buffered gather: kst[b][t2] = K[ki(n16)][16*t2+quad*4 .. +3] (8B)
  s16x4 kst[2][8];
  int   kio[2];
#define STAGE(T, B)                                                           \
  {                                                                           \
    int ki0 = tk[(T) * 16 + n16];                                             \
    kio[B] = ki0;                                                             \
    int ki = ki0 < 0 ? 0 : ki0;                                               \
    const char* rp = (const char*)kvb + (size_t)ki * 256 + quad * 8;          \
    _Pragma("unroll") for (int t2 = 0; t2 < 8; ++t2)                          \
        kst[B][t2] = *(const s16x4*)(rp + t2 * 32);                           \
  }

  STAGE(0, 0)

  // ================= key loop: 8 tiles x 16 keys, no LDS =================
#pragma unroll
  for (int t = 0; t < 8; ++t) {
    const int b = t & 1;
    if (t < 7) STAGE(t + 1, b ^ 1)

    // ---- QK: S[h][key=n16] over 8 K=16 slices (two parallel accumulators) ----
    f32x4 sa0 = (f32x4){0.f, 0.f, 0.f, 0.f};
    f32x4 sa1 = (f32x4){0.f, 0.f, 0.f, 0.f};
#pragma unroll
    for (int c = 0; c < 4; ++c) {
      sa0 = __builtin_amdgcn_mfma_f32_16x16x16bf16_1k(qf[c], kst[b][c], sa0, 0, 0, 0);
      sa1 = __builtin_amdgcn_mfma_f32_16x16x16bf16_1k(qf[4 + c], kst[b][4 + c], sa1, 0, 0, 0);
    }
    float bias = (kio[b] < 0) ? -30000.0f : 0.0f;
    float p0 = __builtin_amdgcn_exp2f(sa0[0] + sa1[0] + bias);
    float p1 = __builtin_amdgcn_exp2f(sa0[1] + sa1[1] + bias);
    float p2 = __builtin_amdgcn_exp2f(sa0[2] + sa1[2] + bias);
    float p3 = __builtin_amdgcn_exp2f(sa0[3] + sa1[3] + bias);

    // ---- P transpose via identity-MFMA: A2[m=key][k=head] * I -> C-layout ----
    s16x4 a2 = mk_s16x4(pk_hi16(p0, p1), pk_hi16(p2, p3));   // RTZ bf16 pack
    f32x4 pt = __builtin_amdgcn_mfma_f32_16x16x16bf16_1k(
        a2, id_f, (f32x4){0.f, 0.f, 0.f, 0.f}, 0, 0, 0);
    s16x4 pf = mk_s16x4(pk_hi16(pt[0], pt[1]), pk_hi16(pt[2], pt[3]));  // exact

    o_l = __builtin_amdgcn_mfma_f32_16x16x16bf16_1k(pf, ones_f, o_l, 0, 0, 0);

    // ---- V transpose (exact) + PV, per 16-d slice ----
#pragma unroll
    for (int dt = 0; dt < 8; ++dt) {
      f32x4 tv = __builtin_amdgcn_mfma_f32_16x16x16bf16_1k(
          kst[b][dt], id_f, (f32x4){0.f, 0.f, 0.f, 0.f}, 0, 0, 0);
      s16x4 vf = mk_s16x4(pk_hi16(tv[0], tv[1]), pk_hi16(tv[2], tv[3]));
      o_acc[dt] = __builtin_amdgcn_mfma_f32_16x16x16bf16_1k(pf, vf, o_acc[dt], 0, 0, 0);
    }
  }
#undef STAGE

  // ================= cross-wave combine: two-round LDS reduce =================
  float* dst = (wave & 1) ? OB : OA;
  if (wave < 2) {
#pragma unroll
    for (int dt = 0; dt < 8; ++dt)
#pragma unroll
      for (int r = 0; r < 4; ++r)
        dst[(quad * 4 + r) * 132 + dt * 16 + n16] = o_acc[dt][r];
  }
  if (n16 == 0) {
#pragma unroll
    for (int r = 0; r < 4; ++r) lsum[wave * 16 + quad * 4 + r] = o_l[r];
  }
  __syncthreads();
  if (wave >= 2) {
#pragma unroll
    for (int dt = 0; dt < 8; ++dt)
#pragma unroll
      for (int r = 0; r < 4; ++r) {
        int idx = (quad * 4 + r) * 132 + dt * 16 + n16;
        dst[idx] += o_acc[dt][r];
      }
  }
  __syncthreads();

  float* outp = outg + (size_t)s * (N_HEADS * D_HEAD);
#pragma unroll
  for (int i = 0; i < 8; ++i) {
    int e = i * 256 + tid;               // 0..2047
    int h = e >> 7, d = e & 127;
    float ls = lsum[h] + lsum[16 + h] + lsum[32 + h] + lsum[48 + h];
    outp[e] = (OA[h * 132 + d] + OB[h * 132 + d]) / ls;
  }
}

extern "C" void kernel_launch(void* const* d_in, const int* in_sizes, int n_in,
                              void* d_out, int out_size, void* d_ws, size_t ws_size,
                              hipStream_t stream) {
  const float* q    = (const float*)d_in[0];
  const float* kv   = (const float*)d_in[1];
  const int*   topk = (const int*)d_in[2];
  float*       out  = (float*)d_out;
  unsigned short* kvb = (unsigned short*)d_ws;   // 8192*128*2 = 2 MB scratch

  kv_cvt_bf16<<<dim3(512), dim3(256), 0, stream>>>(kv, kvb);
  g2core_sparse_attn<<<dim3(S_LEN), dim3(256), 0, stream>>>(q, kvb, topk, out);
}

// Round 7
// 102.033 us; speedup vs baseline: 1.3513x; 1.3513x over previous
//
#include <hip/hip_runtime.h>
#include <stdint.h>

// Sparse top-k attention, B=1 S=2048 H=16 D=128 N_KV=8192 K=512.
// R7: row-cooperative DMA gather. R2-R6 analysis: the dominant cost is
// address-divergence in the gather (~1 segment/cyc/CU). Per-lane-row loads
// cost 64 seg/instr (R5: 27us, R6: 54us of pure segment processing);
// cooperative 4-rows-per-instruction global_load_lds costs 16 -> ~7us.
// Double-buffered LDS tiles, pipelined with s_waitcnt vmcnt(4) (not R2's
// serializing vmcnt(0)). LDS layout: groups of 4 rows, stride 1056B =
// contiguous per-DMA 1024B + 32B inter-group skew -> K ds_read_b128 frags
// dense-minimal AND V u16 column reads conflict-free (banks 8q+8dt+n16/2).
// QK 16x16x32 from LDS; P transpose via identity-MFMA (R6, verified); PV
// 16x16x16. Zero barriers in the key loop.

typedef float  f32x4 __attribute__((ext_vector_type(4)));
typedef short  s16x8 __attribute__((ext_vector_type(8)));
typedef short  s16x4 __attribute__((ext_vector_type(4)));

#define S_LEN   2048
#define N_HEADS 16
#define D_HEAD  128
#define TOPK    512

// LDS map (bytes):
//  [0,33792)   KV tiles: wave w at w*8448; buffer b at +b*4224;
//              row r at (r>>2)*1056 + (r&3)*256 (256B bf16 data/row)
//              (epilogue reuse: OA [16][132] f32 = 8448B at 0 (= wave0's
//               region), OB at 8448 (= wave1's region))
//  [33792,34048) lsum [4][16] f32
#define KV_WAVE   8448
#define KV_BUF    4224
#define LSUM_BASE 33792
#define SMEM_BYTES 34048

#define WAIT_VM4 asm volatile("s_waitcnt vmcnt(4)" ::: "memory")
#define WAIT_VM0 asm volatile("s_waitcnt vmcnt(0)" ::: "memory")

// fp32 -> bf16 round-nearest-even
__device__ __forceinline__ unsigned short f2bf(float f) {
  union { float f; unsigned u; } v; v.f = f;
  return (unsigned short)((v.u + 0x7fffu + ((v.u >> 16) & 1u)) >> 16);
}

// pack high16(lo_elem), high16(hi_elem) -> [hi16(hi)|hi16(lo)] (RTZ bf16 pair)
__device__ __forceinline__ unsigned pk_hi16(float lo, float hi) {
  union { float f; unsigned u; } a, b;
  a.f = lo; b.f = hi;
  return __builtin_amdgcn_perm(b.u, a.u, 0x07060302u);
}

__device__ __forceinline__ s16x4 mk_s16x4(unsigned u0, unsigned u1) {
  union { unsigned u[2]; s16x4 v; } x;
  x.u[0] = u0; x.u[1] = u1;
  return x.v;
}

__global__ void __launch_bounds__(256) kv_cvt_bf16(
    const float* __restrict__ kv, unsigned short* __restrict__ o) {
  int i = (blockIdx.x * 256 + threadIdx.x) * 8;   // 8192*128 = 1M elems, grid 512
  float4 a = *(const float4*)(kv + i);
  float4 b = *(const float4*)(kv + i + 4);
  uint4 p;
  p.x = (unsigned)f2bf(a.x) | ((unsigned)f2bf(a.y) << 16);
  p.y = (unsigned)f2bf(a.z) | ((unsigned)f2bf(a.w) << 16);
  p.z = (unsigned)f2bf(b.x) | ((unsigned)f2bf(b.y) << 16);
  p.w = (unsigned)f2bf(b.z) | ((unsigned)f2bf(b.w) << 16);
  *(uint4*)(o + i) = p;
}

__global__ void __launch_bounds__(256, 4) g2core_sparse_attn(
    const float* __restrict__ qg, const unsigned short* __restrict__ kvb,
    const int* __restrict__ tkg, float* __restrict__ outg) {
  __shared__ __align__(16) char smem[SMEM_BYTES];
  float* OA   = (float*)smem;                 // [16][132]
  float* OB   = (float*)(smem + 8448);        // [16][132]
  float* lsum = (float*)(smem + LSUM_BASE);   // [4][16]

  const int s    = blockIdx.x;
  const int tid  = threadIdx.x;
  const int wave = __builtin_amdgcn_readfirstlane(tid >> 6);
  const int lane = tid & 63;
  const int quad = lane >> 4;   // 0..3
  const int n16  = lane & 15;   // 0..15

  char* kv_base = smem + wave * KV_WAVE;

  // fold 1/sqrt(128) * log2(e) into Q; softmax runs unnormalized in exp2 domain
  const float QSCALE = 0.08838834764831845f * 1.4426950408889634f;

  // ---- Q A-frags (16x16x32): A[m=head=n16][k=32c+8*quad+j] ----
  s16x8 qf[4];
  {
    const float* qrow = qg + ((size_t)s * N_HEADS + n16) * D_HEAD;
#pragma unroll
    for (int c = 0; c < 4; ++c) {
      const float* p0 = qrow + c * 32 + quad * 8;
      float4 a = *(const float4*)(p0);
      float4 b = *(const float4*)(p0 + 4);
      s16x8 f;
      f[0] = (short)f2bf(a.x * QSCALE); f[1] = (short)f2bf(a.y * QSCALE);
      f[2] = (short)f2bf(a.z * QSCALE); f[3] = (short)f2bf(a.w * QSCALE);
      f[4] = (short)f2bf(b.x * QSCALE); f[5] = (short)f2bf(b.y * QSCALE);
      f[6] = (short)f2bf(b.z * QSCALE); f[7] = (short)f2bf(b.w * QSCALE);
      qf[c] = f;
    }
  }

  // identity B-frag (16x16x16): B[k][n] = (k==n)
  s16x4 id_f;
  {
    unsigned u0 = (n16 == quad * 4 + 0 ? 0x3F80u : 0u) | (n16 == quad * 4 + 1 ? 0x3F800000u : 0u);
    unsigned u1 = (n16 == quad * 4 + 2 ? 0x3F80u : 0u) | (n16 == quad * 4 + 3 ? 0x3F800000u : 0u);
    id_f = mk_s16x4(u0, u1);
  }
  // ones-column B-frag (16x16x16): B[k][0]=1 else 0
  s16x4 ones_f;
  {
    unsigned o01 = (n16 == 0) ? 0x3F803F80u : 0u;
    ones_f = mk_s16x4(o01, o01);
  }

  f32x4 o_acc[8];
  f32x4 o_l = (f32x4){0.f, 0.f, 0.f, 0.f};
#pragma unroll
  for (int t = 0; t < 8; ++t) o_acc[t] = (f32x4){0.f, 0.f, 0.f, 0.f};

  // ---- preload all 128 key indices (lane n16 -> key n16 of each tile) ----
  const int* tk = tkg + (size_t)s * TOPK + wave * 128;
  int il[8];
#pragma unroll
  for (int t = 0; t < 8; ++t) il[t] = tk[t * 16 + n16];

  WAIT_VM0;   // drain q/idx loads: from here vmcnt counts ONLY DMA gathers

  // cooperative DMA: instr i loads rows (keys) i*4+0..3, lane covers 16B of one row
#define ISSUE_DMA(TT)                                                         \
  {                                                                           \
    char* dstb = kv_base + ((TT) & 1) * KV_BUF;                               \
    _Pragma("unroll") for (int i = 0; i < 4; ++i) {                           \
      int kk = __shfl(il[TT], i * 4 + quad, 64);                              \
      kk = kk < 0 ? 0 : kk;                                                   \
      const unsigned int* srcp =                                              \
          (const unsigned int*)kvb + (size_t)kk * 64 + n16 * 4;               \
      unsigned int* dstp = (unsigned int*)(dstb + i * 1056);                  \
      __builtin_amdgcn_global_load_lds(                                       \
          (const __attribute__((address_space(1))) unsigned int*)srcp,        \
          (__attribute__((address_space(3))) unsigned int*)dstp, 16, 0, 0);   \
    }                                                                         \
  }

  ISSUE_DMA(0)

  // ================= key loop: 8 tiles x 16 keys, wave-private =================
#pragma unroll
  for (int tt = 0; tt < 8; ++tt) {
    if (tt < 7) { ISSUE_DMA(tt + 1) WAIT_VM4; } else { WAIT_VM0; }
    const char* bufp = kv_base + (tt & 1) * KV_BUF;

    // ---- QK (16x16x32 over d): K B-frags via dense ds_read_b128 ----
    const char* krow = bufp + (n16 >> 2) * 1056 + (n16 & 3) * 256 + quad * 16;
    f32x4 sa = (f32x4){0.f, 0.f, 0.f, 0.f};
#pragma unroll
    for (int c = 0; c < 4; ++c) {
      s16x8 kc = *(const s16x8*)(krow + c * 64);
      sa = __builtin_amdgcn_mfma_f32_16x16x32_bf16(qf[c], kc, sa, 0, 0, 0);
    }
    float bias = (il[tt] < 0) ? -30000.0f : 0.0f;
    float p0 = __builtin_amdgcn_exp2f(sa[0] + bias);
    float p1 = __builtin_amdgcn_exp2f(sa[1] + bias);
    float p2 = __builtin_amdgcn_exp2f(sa[2] + bias);
    float p3 = __builtin_amdgcn_exp2f(sa[3] + bias);

    // ---- P transpose via identity-MFMA: lane=key,regs=head -> lane=head,regs=key
    s16x4 a2 = mk_s16x4(pk_hi16(p0, p1), pk_hi16(p2, p3));   // RTZ bf16 pack
    f32x4 pt = __builtin_amdgcn_mfma_f32_16x16x16bf16_1k(
        a2, id_f, (f32x4){0.f, 0.f, 0.f, 0.f}, 0, 0, 0);
    s16x4 pf = mk_s16x4(pk_hi16(pt[0], pt[1]), pk_hi16(pt[2], pt[3]));  // exact

    o_l = __builtin_amdgcn_mfma_f32_16x16x16bf16_1k(pf, ones_f, o_l, 0, 0, 0);

    // ---- PV (16x16x16): V column reads conflict-free by layout ----
    const unsigned short* vq = (const unsigned short*)(bufp + quad * 1056);
#pragma unroll
    for (int dt = 0; dt < 8; ++dt) {
      const unsigned short* vp = vq + dt * 16 + n16;
      s16x4 vf;
#pragma unroll
      for (int j = 0; j < 4; ++j) vf[j] = (short)vp[j * 128];   // +256B/row
      o_acc[dt] = __builtin_amdgcn_mfma_f32_16x16x16bf16_1k(pf, vf, o_acc[dt], 0, 0, 0);
    }
  }
#undef ISSUE_DMA

  // ================= cross-wave combine: two-round LDS reduce =================
  // pre-sync, each wave writes only its own KV region (OA=wave0's, OB=wave1's)
  float* dst = (wave & 1) ? OB : OA;
  if (wave < 2) {
#pragma unroll
    for (int dt = 0; dt < 8; ++dt)
#pragma unroll
      for (int r = 0; r < 4; ++r)
        dst[(quad * 4 + r) * 132 + dt * 16 + n16] = o_acc[dt][r];
  }
  if (n16 == 0) {
#pragma unroll
    for (int r = 0; r < 4; ++r) lsum[wave * 16 + quad * 4 + r] = o_l[r];
  }
  __syncthreads();
  if (wave >= 2) {
#pragma unroll
    for (int dt = 0; dt < 8; ++dt)
#pragma unroll
      for (int r = 0; r < 4; ++r) {
        int idx = (quad * 4 + r) * 132 + dt * 16 + n16;
        dst[idx] += o_acc[dt][r];
      }
  }
  __syncthreads();

  float* outp = outg + (size_t)s * (N_HEADS * D_HEAD);
#pragma unroll
  for (int i = 0; i < 8; ++i) {
    int e = i * 256 + tid;               // 0..2047
    int h = e >> 7, d = e & 127;
    float ls = lsum[h] + lsum[16 + h] + lsum[32 + h] + lsum[48 + h];
    outp[e] = (OA[h * 132 + d] + OB[h * 132 + d]) / ls;
  }
}

extern "C" void kernel_launch(void* const* d_in, const int* in_sizes, int n_in,
                              void* d_out, int out_size, void* d_ws, size_t ws_size,
                              hipStream_t stream) {
  const float* q    = (const float*)d_in[0];
  const float* kv   = (const float*)d_in[1];
  const int*   topk = (const int*)d_in[2];
  float*       out  = (float*)d_out;
  unsigned short* kvb = (unsigned short*)d_ws;   // 8192*128*2 = 2 MB scratch

  kv_cvt_bf16<<<dim3(512), dim3(256), 0, stream>>>(kv, kvb);
  g2core_sparse_attn<<<dim3(S_LEN), dim3(256), 0, stream>>>(q, kvb, topk, out);
}

// Round 8
// 100.511 us; speedup vs baseline: 1.3718x; 1.0151x over previous
//
#include <hip/hip_runtime.h>
#include <stdint.h>

// Sparse top-k attention, B=1 S=2048 H=16 D=128 N_KV=8192 K=512.
// R8 = R7 (row-cooperative global_load_lds gather, double-buffered,
// vmcnt(4) pipelining) + V-fragment generation by identity-MFMA transpose
// of the ALREADY-LOADED K row registers (K==V). This deletes the last
// DS-pipe tax: 256 scalar ds_read_u16 per wave (~10us/CU serialized).
// Per tile the only LDS reads left are the 4 dense ds_read_b128 for QK.
// V transpose is bit-exact (identity-MFMA on bf16-origin data + RTZ pack).
// QK 16x16x32; P transpose via identity-MFMA (verified R6); PV 16x16x16.
// Zero barriers in the key loop.

typedef float  f32x4 __attribute__((ext_vector_type(4)));
typedef short  s16x8 __attribute__((ext_vector_type(8)));
typedef short  s16x4 __attribute__((ext_vector_type(4)));

#define S_LEN   2048
#define N_HEADS 16
#define D_HEAD  128
#define TOPK    512

// LDS map (bytes):
//  [0,33792)   KV tiles: wave w at w*8448; buffer b at +b*4224;
//              row r at (r>>2)*1056 + (r&3)*256 (256B bf16 data/row)
//              (epilogue reuse: OA [16][132] f32 = 8448B at 0, OB at 8448)
//  [33792,34048) lsum [4][16] f32
#define KV_WAVE   8448
#define KV_BUF    4224
#define LSUM_BASE 33792
#define SMEM_BYTES 34048

#define WAIT_VM4 asm volatile("s_waitcnt vmcnt(4)" ::: "memory")
#define WAIT_VM0 asm volatile("s_waitcnt vmcnt(0)" ::: "memory")

// fp32 -> bf16 round-nearest-even
__device__ __forceinline__ unsigned short f2bf(float f) {
  union { float f; unsigned u; } v; v.f = f;
  return (unsigned short)((v.u + 0x7fffu + ((v.u >> 16) & 1u)) >> 16);
}

// pack high16(lo_elem), high16(hi_elem) -> [hi16(hi)|hi16(lo)] (RTZ bf16 pair)
__device__ __forceinline__ unsigned pk_hi16(float lo, float hi) {
  union { float f; unsigned u; } a, b;
  a.f = lo; b.f = hi;
  return __builtin_amdgcn_perm(b.u, a.u, 0x07060302u);
}

__device__ __forceinline__ s16x4 mk_s16x4(unsigned u0, unsigned u1) {
  union { unsigned u[2]; s16x4 v; } x;
  x.u[0] = u0; x.u[1] = u1;
  return x.v;
}

__global__ void __launch_bounds__(256) kv_cvt_bf16(
    const float* __restrict__ kv, unsigned short* __restrict__ o) {
  int i = (blockIdx.x * 256 + threadIdx.x) * 8;   // 8192*128 = 1M elems, grid 512
  float4 a = *(const float4*)(kv + i);
  float4 b = *(const float4*)(kv + i + 4);
  uint4 p;
  p.x = (unsigned)f2bf(a.x) | ((unsigned)f2bf(a.y) << 16);
  p.y = (unsigned)f2bf(a.z) | ((unsigned)f2bf(a.w) << 16);
  p.z = (unsigned)f2bf(b.x) | ((unsigned)f2bf(b.y) << 16);
  p.w = (unsigned)f2bf(b.z) | ((unsigned)f2bf(b.w) << 16);
  *(uint4*)(o + i) = p;
}

__global__ void __launch_bounds__(256, 4) g2core_sparse_attn(
    const float* __restrict__ qg, const unsigned short* __restrict__ kvb,
    const int* __restrict__ tkg, float* __restrict__ outg) {
  __shared__ __align__(16) char smem[SMEM_BYTES];
  float* OA   = (float*)smem;                 // [16][132]
  float* OB   = (float*)(smem + 8448);        // [16][132]
  float* lsum = (float*)(smem + LSUM_BASE);   // [4][16]

  const int s    = blockIdx.x;
  const int tid  = threadIdx.x;
  const int wave = __builtin_amdgcn_readfirstlane(tid >> 6);
  const int lane = tid & 63;
  const int quad = lane >> 4;   // 0..3
  const int n16  = lane & 15;   // 0..15

  char* kv_base = smem + wave * KV_WAVE;

  // fold 1/sqrt(128) * log2(e) into Q; softmax runs unnormalized in exp2 domain
  const float QSCALE = 0.08838834764831845f * 1.4426950408889634f;

  // ---- Q A-frags (16x16x32): A[m=head=n16][k=32c+8*quad+j] ----
  s16x8 qf[4];
  {
    const float* qrow = qg + ((size_t)s * N_HEADS + n16) * D_HEAD;
#pragma unroll
    for (int c = 0; c < 4; ++c) {
      const float* p0 = qrow + c * 32 + quad * 8;
      float4 a = *(const float4*)(p0);
      float4 b = *(const float4*)(p0 + 4);
      s16x8 f;
      f[0] = (short)f2bf(a.x * QSCALE); f[1] = (short)f2bf(a.y * QSCALE);
      f[2] = (short)f2bf(a.z * QSCALE); f[3] = (short)f2bf(a.w * QSCALE);
      f[4] = (short)f2bf(b.x * QSCALE); f[5] = (short)f2bf(b.y * QSCALE);
      f[6] = (short)f2bf(b.z * QSCALE); f[7] = (short)f2bf(b.w * QSCALE);
      qf[c] = f;
    }
  }

  // identity B-frags for 16x16x32 transpose: lane n16, elem j at k=quad*8+j
  // id_lo: B[k][n]=(k==n)  (k<16, quads 0-1); id_hi: B[k][n]=(k==n+16)
  s16x8 id_lo, id_hi;
#pragma unroll
  for (int j = 0; j < 8; ++j) {
    id_lo[j] = (quad * 8 + j == n16)      ? (short)0x3F80 : (short)0;
    id_hi[j] = (quad * 8 + j == n16 + 16) ? (short)0x3F80 : (short)0;
  }
  // identity B-frag (16x16x16) for the P transpose
  s16x4 id16;
  {
    unsigned u0 = (n16 == quad * 4 + 0 ? 0x3F80u : 0u) | (n16 == quad * 4 + 1 ? 0x3F800000u : 0u);
    unsigned u1 = (n16 == quad * 4 + 2 ? 0x3F80u : 0u) | (n16 == quad * 4 + 3 ? 0x3F800000u : 0u);
    id16 = mk_s16x4(u0, u1);
  }
  // ones-column B-frag (16x16x16): B[k][0]=1 else 0
  s16x4 ones_f;
  {
    unsigned o01 = (n16 == 0) ? 0x3F803F80u : 0u;
    ones_f = mk_s16x4(o01, o01);
  }

  f32x4 o_acc[8];
  f32x4 o_l = (f32x4){0.f, 0.f, 0.f, 0.f};
#pragma unroll
  for (int t = 0; t < 8; ++t) o_acc[t] = (f32x4){0.f, 0.f, 0.f, 0.f};

  // ---- preload all 128 key indices (lane n16 -> key n16 of each tile) ----
  const int* tk = tkg + (size_t)s * TOPK + wave * 128;
  int il[8];
#pragma unroll
  for (int t = 0; t < 8; ++t) il[t] = tk[t * 16 + n16];

  WAIT_VM0;   // drain q/idx loads: from here vmcnt counts ONLY DMA gathers

  // cooperative DMA: instr i loads rows (keys) i*4+0..3, lane covers 16B of one row
#define ISSUE_DMA(TT)                                                         \
  {                                                                           \
    char* dstb = kv_base + ((TT) & 1) * KV_BUF;                               \
    _Pragma("unroll") for (int i = 0; i < 4; ++i) {                           \
      int kk = __shfl(il[TT], i * 4 + quad, 64);                              \
      kk = kk < 0 ? 0 : kk;                                                   \
      const unsigned int* srcp =                                              \
          (const unsigned int*)kvb + (size_t)kk * 64 + n16 * 4;               \
      unsigned int* dstp = (unsigned int*)(dstb + i * 1056);                  \
      __builtin_amdgcn_global_load_lds(                                       \
          (const __attribute__((address_space(1))) unsigned int*)srcp,        \
          (__attribute__((address_space(3))) unsigned int*)dstp, 16, 0, 0);   \
    }                                                                         \
  }

  ISSUE_DMA(0)

  // ================= key loop: 8 tiles x 16 keys, wave-private =================
#pragma unroll
  for (int tt = 0; tt < 8; ++tt) {
    if (tt < 7) { ISSUE_DMA(tt + 1) WAIT_VM4; } else { WAIT_VM0; }
    const char* bufp = kv_base + (tt & 1) * KV_BUF;

    // ---- read this lane's key row once: kc[c] = KV[key=n16][32c+quad*8..+7] ----
    const char* krow = bufp + (n16 >> 2) * 1056 + (n16 & 3) * 256 + quad * 16;
    s16x8 kc[4];
#pragma unroll
    for (int c = 0; c < 4; ++c) kc[c] = *(const s16x8*)(krow + c * 64);

    // ---- QK (16x16x32 over d): S[h=quad*4+r][key=n16] ----
    f32x4 sa = (f32x4){0.f, 0.f, 0.f, 0.f};
#pragma unroll
    for (int c = 0; c < 4; ++c)
      sa = __builtin_amdgcn_mfma_f32_16x16x32_bf16(qf[c], kc[c], sa, 0, 0, 0);
    float bias = (il[tt] < 0) ? -30000.0f : 0.0f;
    float p0 = __builtin_amdgcn_exp2f(sa[0] + bias);
    float p1 = __builtin_amdgcn_exp2f(sa[1] + bias);
    float p2 = __builtin_amdgcn_exp2f(sa[2] + bias);
    float p3 = __builtin_amdgcn_exp2f(sa[3] + bias);

    // ---- P transpose via identity-MFMA: lane=key,regs=head -> lane=head,regs=key
    s16x4 a2 = mk_s16x4(pk_hi16(p0, p1), pk_hi16(p2, p3));   // RTZ bf16 pack
    f32x4 pt = __builtin_amdgcn_mfma_f32_16x16x16bf16_1k(
        a2, id16, (f32x4){0.f, 0.f, 0.f, 0.f}, 0, 0, 0);
    s16x4 pf = mk_s16x4(pk_hi16(pt[0], pt[1]), pk_hi16(pt[2], pt[3]));  // exact

    o_l = __builtin_amdgcn_mfma_f32_16x16x16bf16_1k(pf, ones_f, o_l, 0, 0, 0);

    // ---- V B-frags by transposing kc[c] (K==V, rows already in registers):
    //      mfma(kc[c], id_lo) -> D[key][32c+n] in C-layout = PV B-frag dt=2c
    //      mfma(kc[c], id_hi) -> dt=2c+1.  Bit-exact; no LDS reads. ----
#pragma unroll
    for (int c = 0; c < 4; ++c) {
      f32x4 tv0 = __builtin_amdgcn_mfma_f32_16x16x32_bf16(
          kc[c], id_lo, (f32x4){0.f, 0.f, 0.f, 0.f}, 0, 0, 0);
      f32x4 tv1 = __builtin_amdgcn_mfma_f32_16x16x32_bf16(
          kc[c], id_hi, (f32x4){0.f, 0.f, 0.f, 0.f}, 0, 0, 0);
      s16x4 vf0 = mk_s16x4(pk_hi16(tv0[0], tv0[1]), pk_hi16(tv0[2], tv0[3]));
      s16x4 vf1 = mk_s16x4(pk_hi16(tv1[0], tv1[1]), pk_hi16(tv1[2], tv1[3]));
      o_acc[2 * c]     = __builtin_amdgcn_mfma_f32_16x16x16bf16_1k(pf, vf0, o_acc[2 * c], 0, 0, 0);
      o_acc[2 * c + 1] = __builtin_amdgcn_mfma_f32_16x16x16bf16_1k(pf, vf1, o_acc[2 * c + 1], 0, 0, 0);
    }
  }
#undef ISSUE_DMA

  // ================= cross-wave combine: two-round LDS reduce =================
  // pre-sync, each wave writes only its own KV region (OA=wave0's, OB=wave1's)
  float* dst = (wave & 1) ? OB : OA;
  if (wave < 2) {
#pragma unroll
    for (int dt = 0; dt < 8; ++dt)
#pragma unroll
      for (int r = 0; r < 4; ++r)
        dst[(quad * 4 + r) * 132 + dt * 16 + n16] = o_acc[dt][r];
  }
  if (n16 == 0) {
#pragma unroll
    for (int r = 0; r < 4; ++r) lsum[wave * 16 + quad * 4 + r] = o_l[r];
  }
  __syncthreads();
  if (wave >= 2) {
#pragma unroll
    for (int dt = 0; dt < 8; ++dt)
#pragma unroll
      for (int r = 0; r < 4; ++r) {
        int idx = (quad * 4 + r) * 132 + dt * 16 + n16;
        dst[idx] += o_acc[dt][r];
      }
  }
  __syncthreads();

  float* outp = outg + (size_t)s * (N_HEADS * D_HEAD);
#pragma unroll
  for (int i = 0; i < 8; ++i) {
    int e = i * 256 + tid;               // 0..2047
    int h = e >> 7, d = e & 127;
    float ls = lsum[h] + lsum[16 + h] + lsum[32 + h] + lsum[48 + h];
    outp[e] = (OA[h * 132 + d] + OB[h * 132 + d]) / ls;
  }
}

extern "C" void kernel_launch(void* const* d_in, const int* in_sizes, int n_in,
                              void* d_out, int out_size, void* d_ws, size_t ws_size,
                              hipStream_t stream) {
  const float* q    = (const float*)d_in[0];
  const float* kv   = (const float*)d_in[1];
  const int*   topk = (const int*)d_in[2];
  float*       out  = (float*)d_out;
  unsigned short* kvb = (unsigned short*)d_ws;   // 8192*128*2 = 2 MB scratch

  kv_cvt_bf16<<<dim3(512), dim3(256), 0, stream>>>(kv, kvb);
  g2core_sparse_attn<<<dim3(S_LEN), dim3(256), 0, stream>>>(q, kvb, topk, out);
}